// Round 15
// baseline (42.863 us; speedup 1.0000x reference)
//
#include <hip/hip_runtime.h>
#include <math.h>

// r0 = M^-1 b (masked), b = 2*(1 - e_s), sum b = 1022, M = 1.1 I + J (511-dim)
#define ZINIT ((2.0f - 1022.0f / 512.1f) * (1.0f / 1.1f))
// Degree-3 residual-poly roots theta = {1, 1/11, 21/11} (duplicate outliers exact):
//   s1 = s0 - u0;  s2 = s1 - 11*u1;   x = s0 + 11*s1 + (11/21)*s2
// r1 is pointwise-recomputable: r1[s,j] = f(D_j, D_s, SD, K[s,j]) -- no R/X arrays.
// 3 nodes: rbf -> matmul -> fin3 (loss via one float atomicAdd; out zeroed in rbf).

// ---------------- block-wide reductions over 256 threads ----------------
__device__ __forceinline__ float bsum1(float v, volatile float* red) {
  #pragma unroll
  for (int o = 32; o; o >>= 1) v += __shfl_down(v, o, 64);
  __syncthreads();
  if ((threadIdx.x & 63) == 0) red[threadIdx.x >> 6] = v;
  __syncthreads();
  return red[0] + red[1] + red[2] + red[3];
}

__device__ __forceinline__ void bsum2(float a, float b, volatile float* red,
                                      float& ra, float& rb) {
  #pragma unroll
  for (int o = 32; o; o >>= 1) { a += __shfl_down(a, o, 64); b += __shfl_down(b, o, 64); }
  __syncthreads();
  if ((threadIdx.x & 63) == 0) { int w = threadIdx.x >> 6; red[w] = a; red[4 + w] = b; }
  __syncthreads();
  ra = red[0] + red[1] + red[2] + red[3];
  rb = red[4] + red[5] + red[6] + red[7];
}

__device__ __forceinline__ void bsum3(float a, float b, float c, volatile float* red,
                                      float& ra, float& rb, float& rc) {
  #pragma unroll
  for (int o = 32; o; o >>= 1) {
    a += __shfl_down(a, o, 64); b += __shfl_down(b, o, 64); c += __shfl_down(c, o, 64);
  }
  __syncthreads();
  if ((threadIdx.x & 63) == 0) { int w = threadIdx.x >> 6; red[w] = a; red[4 + w] = b; red[8 + w] = c; }
  __syncthreads();
  ra = red[0] + red[1] + red[2] + red[3];
  rb = red[4] + red[5] + red[6] + red[7];
  rc = red[8] + red[9] + red[10] + red[11];
}

// ---- K1: fused gather+normalize (LDS) + K (512x1024) + rowsum partials ----
__global__ __launch_bounds__(256) void k_rbf(
    const float* __restrict__ x1, const float* __restrict__ x2,
    const int* __restrict__ i1, const int* __restrict__ i2,
    float* __restrict__ Km, float* __restrict__ rsP, float* __restrict__ out) {
  __shared__ __align__(16) float Z[96][132];  // 132: 16B-aligned rows
  const int blk = blockIdx.x, t = threadIdx.x;
  if (blk == 0 && t == 0) out[0] = 0.0f;  // accumulator for k_fin3's atomics
  const int bj4 = blk & 15;
  const int bi = (blk >> 4) * 32, bj = bj4 * 64;
  const int wv = t >> 6, ln = t & 63;
  for (int i0 = 0; i0 < 24; i0 += 4) {
    float2 v[4];
    #pragma unroll
    for (int e = 0; e < 4; ++e) {
      int row = wv + 4 * (i0 + e);
      int r = (row < 32) ? (bi + row) : (bj + (row - 32));
      const float* src = (r < 512) ? (x1 + (size_t)i1[r] * 128)
                                   : (x2 + (size_t)i2[r - 512] * 128);
      v[e] = *(const float2*)&src[2 * ln];
    }
    #pragma unroll
    for (int e = 0; e < 4; ++e) {
      int row = wv + 4 * (i0 + e);
      float ss = v[e].x * v[e].x + v[e].y * v[e].y;
      #pragma unroll
      for (int o = 1; o < 64; o <<= 1) ss += __shfl_xor(ss, o, 64);
      float inv = 1.0f / fmaxf(sqrtf(ss), 1e-12f);
      Z[row][2 * ln] = v[e].x * inv;
      Z[row][2 * ln + 1] = v[e].y * inv;
    }
  }
  __syncthreads();
  float acc[8] = {};
  #pragma unroll 2
  for (int kk = 0; kk < 128; kk += 4) {  // float4 along kk; add order == scalar order
    float4 bz = *(const float4*)&Z[32 + ln][kk];
    #pragma unroll
    for (int ii = 0; ii < 8; ++ii) {
      float4 za = *(const float4*)&Z[wv + 4 * ii][kk];
      acc[ii] += za.x * bz.x;
      acc[ii] += za.y * bz.y;
      acc[ii] += za.z * bz.z;
      acc[ii] += za.w * bz.w;
    }
  }
  int j = bj + ln;
  float kvs[8];
  #pragma unroll
  for (int ii = 0; ii < 8; ++ii) {
    int i = bi + wv + 4 * ii;
    float d2 = 2.0f - 2.0f * acc[ii];  // unit rows: |z|^2 == 1
    float kv = expf(-d2 * (1.0f / 0.14f));
    kvs[ii] = kv;
    Km[i * 1024 + j] = kv;
  }
  if (bj4 < 8) {  // deterministic partial row sums of K[:, :512]
    #pragma unroll
    for (int ii = 0; ii < 8; ++ii) {
      float v = kvs[ii];
      #pragma unroll
      for (int o = 32; o; o >>= 1) v += __shfl_down(v, o, 64);
      if (ln == 0) rsP[bj4 * 512 + bi + wv + 4 * ii] = v;
    }
  }
}

// ---- K2: Qp[slice] = r1[:, ks:ks+128] * K[ks:ks+128, :512]  (K-split x4) ----
// A-operand r1 generated on the fly from Km + rsP.
__global__ __launch_bounds__(256) void k_matmul(
    const float* __restrict__ Km, const float* __restrict__ rsP,
    float* __restrict__ Qp) {
  __shared__ __align__(16) float smem[2 * 16 * 68];
  float (*Pt)[68] = (float(*)[68])smem;              // [k][m] = r1
  float (*Gt)[68] = (float(*)[68])(smem + 16 * 68);  // [k][n] = K
  __shared__ float Dls[128], sysD[64];
  __shared__ float redv[4];
  const int t = threadIdx.x, blk = blockIdx.x;
  const int tile = blk >> 2, slice = blk & 3;
  const int bm = (tile >> 3) * 64, bn = (tile & 7) * 64;
  const int ks = slice * 128;
  const int m0 = (t >> 4) * 4, n0 = (t & 15) * 4;
  // ---- prologue: D for all 512 cols (thread owns 2), publish needed slices + SD
  const int i0 = 2 * t;
  float D0 = -1.0f, D1 = -1.0f;
  #pragma unroll
  for (int b = 0; b < 8; ++b) {
    float2 rp = *(const float2*)&rsP[b * 512 + i0];
    D0 += rp.x; D1 += rp.y;
  }
  if ((unsigned)(i0 - ks) < 128u) { Dls[i0 - ks] = D0; Dls[i0 - ks + 1] = D1; }
  if ((unsigned)(i0 - bm) < 64u) { sysD[i0 - bm] = D0; sysD[i0 - bm + 1] = D1; }
  const float SD = bsum1(D0 + D1, redv);  // barriers publish Dls/sysD
  const float sig0 = 511.0f * ZINIT;
  float acc[4][4] = {};
  for (int kc = ks; kc < ks + 128; kc += 16) {
    {
      int m = t >> 2, k4 = (t & 3) * 4;
      float4 w4 = *(const float4*)&Km[(size_t)(bm + m) * 1024 + kc + k4];
      const float Ds = sysD[m];
      const float tau0 = ZINIT * Ds;
      const float Sq0 = ZINIT * (SD - Ds) + sig0 * (512.1f - Ds) - 512.0f * tau0;
      const float cu0 = Sq0 * (1.0f / 512.1f);
      #pragma unroll
      for (int e = 0; e < 4; ++e) {
        int j = kc + k4 + e;
        float w = (&w4.x)[e];
        float q = ZINIT * (512.1f + Dls[j - ks] - w) - w * sig0 - tau0;
        float r1 = (j == bm + m) ? 0.0f : (ZINIT - (q - cu0) * (1.0f / 1.1f));
        Pt[k4 + e][m] = r1;
      }
    }
    {
      int k0 = t >> 6, n = t & 63;
      #pragma unroll
      for (int e = 0; e < 4; ++e)
        Gt[k0 + 4 * e][n] = Km[(size_t)(kc + k0 + 4 * e) * 1024 + bn + n];
    }
    __syncthreads();
    #pragma unroll
    for (int kk = 0; kk < 16; ++kk) {
      float4 a = *(const float4*)&Pt[kk][m0];
      float4 b = *(const float4*)&Gt[kk][n0];
      acc[0][0] += a.x * b.x; acc[0][1] += a.x * b.y; acc[0][2] += a.x * b.z; acc[0][3] += a.x * b.w;
      acc[1][0] += a.y * b.x; acc[1][1] += a.y * b.y; acc[1][2] += a.y * b.z; acc[1][3] += a.y * b.w;
      acc[2][0] += a.z * b.x; acc[2][1] += a.z * b.y; acc[2][2] += a.z * b.z; acc[2][3] += a.z * b.w;
      acc[3][0] += a.w * b.x; acc[3][1] += a.w * b.y; acc[3][2] += a.w * b.z; acc[3][3] += a.w * b.w;
    }
    __syncthreads();
  }
  float* Qs = Qp + (size_t)slice * 262144;
  #pragma unroll
  for (int i = 0; i < 4; ++i)
    *(float4*)&Qs[(size_t)(bm + m0 + i) * 512 + bn + n0] =
        make_float4(acc[i][0], acc[i][1], acc[i][2], acc[i][3]);
}

// ---- K3: deg-3 finish (1 system/block): recompute r1 + scalars, s2, x, clip,
//      loss -> one float atomicAdd into out[0] (zeroed by k_rbf). ----
__global__ __launch_bounds__(256) void k_fin3(
    const float* __restrict__ Km, const float* __restrict__ rsP,
    const float* __restrict__ Qp, float* __restrict__ out) {
  __shared__ float red[12];
  const int t = threadIdx.x, s = blockIdx.x;
  const int i0 = 2 * t, i1 = i0 + 1;
  // hoisted long-latency gathers (Ks column + diag): issue first, use last
  const float kv0 = Km[(size_t)i0 * 1024 + 512 + s];
  const float kv1 = Km[(size_t)i1 * 1024 + 512 + s];
  const float diag = Km[(size_t)s * 1024 + 512 + s];
  float D0 = -1.0f, D1 = -1.0f;
  #pragma unroll
  for (int b = 0; b < 8; ++b) {
    float2 rp = *(const float2*)&rsP[b * 512 + i0];
    D0 += rp.x; D1 += rp.y;
  }
  float Ds = -1.0f;
  #pragma unroll
  for (int b = 0; b < 8; ++b) Ds += rsP[b * 512 + s];
  const float SD = bsum1(D0 + D1, red);
  // ---- recompute r1 (same expressions as k_matmul's generator) ----
  const float sig0 = 511.0f * ZINIT;
  const float tau0 = ZINIT * Ds;
  const float Sq0 = ZINIT * (SD - Ds) + sig0 * (512.1f - Ds) - 512.0f * tau0;
  const float cu0 = Sq0 * (1.0f / 512.1f);
  const size_t ro = (size_t)s * 512 + i0;
  float2 w = *(const float2*)&Km[(size_t)s * 1024 + i0];
  const bool m0 = (i0 == s), m1 = (i1 == s);
  float q0 = ZINIT * (512.1f + D0 - w.x) - w.x * sig0 - tau0;
  float q1 = ZINIT * (512.1f + D1 - w.y) - w.y * sig0 - tau0;
  float r1a = m0 ? 0.0f : (ZINIT - (q0 - cu0) * (1.0f / 1.1f));
  float r1b = m1 ? 0.0f : (ZINIT - (q1 - cu0) * (1.0f / 1.1f));
  // ---- per-system scalars ----
  float sg, ta, gm;
  bsum3(r1a + r1b, w.x * r1a + w.y * r1b, D0 * r1a + D1 * r1b, red, sg, ta, gm);
  const float Sq = gm + sg * (512.1f - Ds) - 512.0f * ta;
  const float cu = Sq * (1.0f / 512.1f);
  // ---- combine Qp partials, s2, x, clip, loss ----
  float2 a0 = *(const float2*)&Qp[ro];
  float2 a1 = *(const float2*)&Qp[ro + 262144];
  float2 a2 = *(const float2*)&Qp[ro + 524288];
  float2 a3 = *(const float2*)&Qp[ro + 786432];
  float qs0 = a0.x + a1.x + a2.x + a3.x;
  float qs1 = a0.y + a1.y + a2.y + a3.y;
  float qraw0 = sg + 0.1f * r1a + qs0;
  float qraw1 = sg + 0.1f * r1b + qs1;
  float qq0 = m0 ? 0.0f : (qraw0 - w.x * sg - ta);
  float qq1 = m1 ? 0.0f : (qraw1 - w.y * sg - ta);
  float r2a = m0 ? 0.0f : (r1a - 11.0f * (qq0 - cu) * (1.0f / 1.1f));
  float r2b = m1 ? 0.0f : (r1b - 11.0f * (qq1 - cu) * (1.0f / 1.1f));
  float xva = (m0 ? 0.0f : ZINIT) + 11.0f * r1a;
  float xvb = (m1 ? 0.0f : ZINIT) + 11.0f * r1b;
  float av0 = fminf(fmaxf(xva + (11.0f / 21.0f) * r2a, 0.0f), 1.0f);
  float av1 = fminf(fmaxf(xvb + (11.0f / 21.0f) * r2b, 0.0f), 1.0f);
  float sa, sn;
  bsum2(av0 + av1, av0 * kv0 + av1 * kv1, red, sa, sn);
  if (t == 0) {
    double contrib = (double)sn - (double)sa * (double)diag;
    atomicAdd(out, (float)(contrib * (1.0 / 512.0)));
  }
}

extern "C" void kernel_launch(void* const* d_in, const int* in_sizes, int n_in,
                              void* d_out, int out_size, void* d_ws, size_t ws_size,
                              hipStream_t stream) {
  const float* x1 = (const float*)d_in[0];
  const float* x2 = (const float*)d_in[1];
  const int* i1 = (const int*)d_in[2];
  const int* i2 = (const int*)d_in[3];

  float* ws = (float*)d_ws;
  float* Km  = ws;                    // 512*1024
  float* rsP = Km + 524288;           // 8*512
  float* Qp  = rsP + 4096;            // 4*512*512
  float* out = (float*)d_out;

  k_rbf<<<256, 256, 0, stream>>>(x1, x2, i1, i2, Km, rsP, out);
  k_matmul<<<256, 256, 0, stream>>>(Km, rsP, Qp);
  k_fin3<<<512, 256, 0, stream>>>(Km, rsP, Qp, out);
}

// Round 16
// 38.891 us; speedup vs baseline: 1.1021x; 1.1021x over previous
//
#include <hip/hip_runtime.h>
#include <math.h>

// r0 = M^-1 b (masked), b = 2*(1 - e_s), sum b = 1022, M = 1.1 I + J (511-dim)
#define ZINIT ((2.0f - 1022.0f / 512.1f) * (1.0f / 1.1f))
// Degree-3 residual-poly roots theta = {1, 1/11, 21/11} (duplicate outliers exact):
//   s1 = s0 - u0;  s2 = s1 - 11*u1;   x = s0 + 11*s1 + (11/21)*s2
// r1 is pointwise-recomputable: r1[s,j] = f(D_j, D_s, SD, K[s,j]) -- no R/X arrays.
// 4 nodes: rbf -> matmul -> fin3 -> out (deterministic double contrib reduce).

// ---------------- block-wide reductions over 256 threads ----------------
__device__ __forceinline__ float bsum1(float v, volatile float* red) {
  #pragma unroll
  for (int o = 32; o; o >>= 1) v += __shfl_down(v, o, 64);
  __syncthreads();
  if ((threadIdx.x & 63) == 0) red[threadIdx.x >> 6] = v;
  __syncthreads();
  return red[0] + red[1] + red[2] + red[3];
}

__device__ __forceinline__ void bsum2(float a, float b, volatile float* red,
                                      float& ra, float& rb) {
  #pragma unroll
  for (int o = 32; o; o >>= 1) { a += __shfl_down(a, o, 64); b += __shfl_down(b, o, 64); }
  __syncthreads();
  if ((threadIdx.x & 63) == 0) { int w = threadIdx.x >> 6; red[w] = a; red[4 + w] = b; }
  __syncthreads();
  ra = red[0] + red[1] + red[2] + red[3];
  rb = red[4] + red[5] + red[6] + red[7];
}

__device__ __forceinline__ void bsum3(float a, float b, float c, volatile float* red,
                                      float& ra, float& rb, float& rc) {
  #pragma unroll
  for (int o = 32; o; o >>= 1) {
    a += __shfl_down(a, o, 64); b += __shfl_down(b, o, 64); c += __shfl_down(c, o, 64);
  }
  __syncthreads();
  if ((threadIdx.x & 63) == 0) { int w = threadIdx.x >> 6; red[w] = a; red[4 + w] = b; red[8 + w] = c; }
  __syncthreads();
  ra = red[0] + red[1] + red[2] + red[3];
  rb = red[4] + red[5] + red[6] + red[7];
  rc = red[8] + red[9] + red[10] + red[11];
}

// ---- K1: fused gather+normalize (LDS) + K (512x1024) + rowsum partials ----
__global__ __launch_bounds__(256) void k_rbf(
    const float* __restrict__ x1, const float* __restrict__ x2,
    const int* __restrict__ i1, const int* __restrict__ i2,
    float* __restrict__ Km, float* __restrict__ rsP) {
  __shared__ __align__(16) float Z[96][132];  // 132: 16B-aligned rows, 2-way-max banks
  const int blk = blockIdx.x, t = threadIdx.x;
  const int bj4 = blk & 15;
  const int bi = (blk >> 4) * 32, bj = bj4 * 64;
  const int wv = t >> 6, ln = t & 63;
  for (int i0 = 0; i0 < 24; i0 += 4) {
    float2 v[4];
    #pragma unroll
    for (int e = 0; e < 4; ++e) {
      int row = wv + 4 * (i0 + e);
      int r = (row < 32) ? (bi + row) : (bj + (row - 32));
      const float* src = (r < 512) ? (x1 + (size_t)i1[r] * 128)
                                   : (x2 + (size_t)i2[r - 512] * 128);
      v[e] = *(const float2*)&src[2 * ln];
    }
    #pragma unroll
    for (int e = 0; e < 4; ++e) {
      int row = wv + 4 * (i0 + e);
      float ss = v[e].x * v[e].x + v[e].y * v[e].y;
      #pragma unroll
      for (int o = 1; o < 64; o <<= 1) ss += __shfl_xor(ss, o, 64);
      float inv = 1.0f / fmaxf(sqrtf(ss), 1e-12f);
      Z[row][2 * ln] = v[e].x * inv;
      Z[row][2 * ln + 1] = v[e].y * inv;
    }
  }
  __syncthreads();
  float acc[8] = {};
  #pragma unroll 2
  for (int kk = 0; kk < 128; kk += 4) {  // float4 along kk; add order == scalar order
    float4 bz = *(const float4*)&Z[32 + ln][kk];
    #pragma unroll
    for (int ii = 0; ii < 8; ++ii) {
      float4 za = *(const float4*)&Z[wv + 4 * ii][kk];
      acc[ii] += za.x * bz.x;
      acc[ii] += za.y * bz.y;
      acc[ii] += za.z * bz.z;
      acc[ii] += za.w * bz.w;
    }
  }
  int j = bj + ln;
  float kvs[8];
  #pragma unroll
  for (int ii = 0; ii < 8; ++ii) {
    int i = bi + wv + 4 * ii;
    float d2 = 2.0f - 2.0f * acc[ii];  // unit rows: |z|^2 == 1
    float kv = expf(-d2 * (1.0f / 0.14f));
    kvs[ii] = kv;
    Km[i * 1024 + j] = kv;
  }
  if (bj4 < 8) {  // deterministic partial row sums of K[:, :512]
    #pragma unroll
    for (int ii = 0; ii < 8; ++ii) {
      float v = kvs[ii];
      #pragma unroll
      for (int o = 32; o; o >>= 1) v += __shfl_down(v, o, 64);
      if (ln == 0) rsP[bj4 * 512 + bi + wv + 4 * ii] = v;
    }
  }
}

// ---- K2: Qp[slice] = r1[:, ks:ks+128] * K[ks:ks+128, :512]  (K-split x4) ----
// A-operand r1 generated on the fly from Km + rsP (bit-identical to old upd0).
__global__ __launch_bounds__(256) void k_matmul(
    const float* __restrict__ Km, const float* __restrict__ rsP,
    float* __restrict__ Qp) {
  __shared__ __align__(16) float smem[2 * 16 * 68];
  float (*Pt)[68] = (float(*)[68])smem;              // [k][m] = r1
  float (*Gt)[68] = (float(*)[68])(smem + 16 * 68);  // [k][n] = K
  __shared__ float Dls[128], sysD[64];
  __shared__ float redv[4];
  const int t = threadIdx.x, blk = blockIdx.x;
  const int tile = blk >> 2, slice = blk & 3;
  const int bm = (tile >> 3) * 64, bn = (tile & 7) * 64;
  const int ks = slice * 128;
  const int m0 = (t >> 4) * 4, n0 = (t & 15) * 4;
  // ---- prologue: D for all 512 cols (thread owns 2), publish needed slices + SD
  const int i0 = 2 * t;
  float D0 = -1.0f, D1 = -1.0f;
  #pragma unroll
  for (int b = 0; b < 8; ++b) {
    float2 rp = *(const float2*)&rsP[b * 512 + i0];
    D0 += rp.x; D1 += rp.y;
  }
  if ((unsigned)(i0 - ks) < 128u) { Dls[i0 - ks] = D0; Dls[i0 - ks + 1] = D1; }
  if ((unsigned)(i0 - bm) < 64u) { sysD[i0 - bm] = D0; sysD[i0 - bm + 1] = D1; }
  const float SD = bsum1(D0 + D1, redv);  // barriers publish Dls/sysD
  const float sig0 = 511.0f * ZINIT;
  float acc[4][4] = {};
  for (int kc = ks; kc < ks + 128; kc += 16) {
    {
      int m = t >> 2, k4 = (t & 3) * 4;
      float4 w4 = *(const float4*)&Km[(size_t)(bm + m) * 1024 + kc + k4];
      const float Ds = sysD[m];
      const float tau0 = ZINIT * Ds;
      const float Sq0 = ZINIT * (SD - Ds) + sig0 * (512.1f - Ds) - 512.0f * tau0;
      const float cu0 = Sq0 * (1.0f / 512.1f);
      #pragma unroll
      for (int e = 0; e < 4; ++e) {
        int j = kc + k4 + e;
        float w = (&w4.x)[e];
        float q = ZINIT * (512.1f + Dls[j - ks] - w) - w * sig0 - tau0;
        float r1 = (j == bm + m) ? 0.0f : (ZINIT - (q - cu0) * (1.0f / 1.1f));
        Pt[k4 + e][m] = r1;
      }
    }
    {
      int k0 = t >> 6, n = t & 63;
      #pragma unroll
      for (int e = 0; e < 4; ++e)
        Gt[k0 + 4 * e][n] = Km[(size_t)(kc + k0 + 4 * e) * 1024 + bn + n];
    }
    __syncthreads();
    #pragma unroll
    for (int kk = 0; kk < 16; ++kk) {
      float4 a = *(const float4*)&Pt[kk][m0];
      float4 b = *(const float4*)&Gt[kk][n0];
      acc[0][0] += a.x * b.x; acc[0][1] += a.x * b.y; acc[0][2] += a.x * b.z; acc[0][3] += a.x * b.w;
      acc[1][0] += a.y * b.x; acc[1][1] += a.y * b.y; acc[1][2] += a.y * b.z; acc[1][3] += a.y * b.w;
      acc[2][0] += a.z * b.x; acc[2][1] += a.z * b.y; acc[2][2] += a.z * b.z; acc[2][3] += a.z * b.w;
      acc[3][0] += a.w * b.x; acc[3][1] += a.w * b.y; acc[3][2] += a.w * b.z; acc[3][3] += a.w * b.w;
    }
    __syncthreads();
  }
  float* Qs = Qp + (size_t)slice * 262144;
  #pragma unroll
  for (int i = 0; i < 4; ++i)
    *(float4*)&Qs[(size_t)(bm + m0 + i) * 512 + bn + n0] =
        make_float4(acc[i][0], acc[i][1], acc[i][2], acc[i][3]);
}

// ---- K3: deg-3 finish (1 system/block): recompute r1 + scalars, s2, x, clip,
//      loss -> contrib[s].  NO fence/ticket; k_out reduces. ----
__global__ __launch_bounds__(256) void k_fin3(
    const float* __restrict__ Km, const float* __restrict__ rsP,
    const float* __restrict__ Qp, double* __restrict__ contrib) {
  __shared__ float red[12];
  const int t = threadIdx.x, s = blockIdx.x;
  const int i0 = 2 * t, i1 = i0 + 1;
  // hoisted long-latency gathers (Ks column + diag): issue first, use last
  const float kv0 = Km[(size_t)i0 * 1024 + 512 + s];
  const float kv1 = Km[(size_t)i1 * 1024 + 512 + s];
  const float diag = Km[(size_t)s * 1024 + 512 + s];
  float D0 = -1.0f, D1 = -1.0f;
  #pragma unroll
  for (int b = 0; b < 8; ++b) {
    float2 rp = *(const float2*)&rsP[b * 512 + i0];
    D0 += rp.x; D1 += rp.y;
  }
  float Ds = -1.0f;
  #pragma unroll
  for (int b = 0; b < 8; ++b) Ds += rsP[b * 512 + s];
  const float SD = bsum1(D0 + D1, red);
  // ---- recompute r1 (bit-identical to k_matmul's generator) ----
  const float sig0 = 511.0f * ZINIT;
  const float tau0 = ZINIT * Ds;
  const float Sq0 = ZINIT * (SD - Ds) + sig0 * (512.1f - Ds) - 512.0f * tau0;
  const float cu0 = Sq0 * (1.0f / 512.1f);
  const size_t ro = (size_t)s * 512 + i0;
  float2 w = *(const float2*)&Km[(size_t)s * 1024 + i0];
  const bool m0 = (i0 == s), m1 = (i1 == s);
  float q0 = ZINIT * (512.1f + D0 - w.x) - w.x * sig0 - tau0;
  float q1 = ZINIT * (512.1f + D1 - w.y) - w.y * sig0 - tau0;
  float r1a = m0 ? 0.0f : (ZINIT - (q0 - cu0) * (1.0f / 1.1f));
  float r1b = m1 ? 0.0f : (ZINIT - (q1 - cu0) * (1.0f / 1.1f));
  // ---- per-system scalars ----
  float sg, ta, gm;
  bsum3(r1a + r1b, w.x * r1a + w.y * r1b, D0 * r1a + D1 * r1b, red, sg, ta, gm);
  const float Sq = gm + sg * (512.1f - Ds) - 512.0f * ta;
  const float cu = Sq * (1.0f / 512.1f);
  // ---- combine Qp partials, s2, x, clip, loss ----
  float2 a0 = *(const float2*)&Qp[ro];
  float2 a1 = *(const float2*)&Qp[ro + 262144];
  float2 a2 = *(const float2*)&Qp[ro + 524288];
  float2 a3 = *(const float2*)&Qp[ro + 786432];
  float qs0 = a0.x + a1.x + a2.x + a3.x;
  float qs1 = a0.y + a1.y + a2.y + a3.y;
  float qraw0 = sg + 0.1f * r1a + qs0;
  float qraw1 = sg + 0.1f * r1b + qs1;
  float qq0 = m0 ? 0.0f : (qraw0 - w.x * sg - ta);
  float qq1 = m1 ? 0.0f : (qraw1 - w.y * sg - ta);
  float r2a = m0 ? 0.0f : (r1a - 11.0f * (qq0 - cu) * (1.0f / 1.1f));
  float r2b = m1 ? 0.0f : (r1b - 11.0f * (qq1 - cu) * (1.0f / 1.1f));
  float xva = (m0 ? 0.0f : ZINIT) + 11.0f * r1a;
  float xvb = (m1 ? 0.0f : ZINIT) + 11.0f * r1b;
  float av0 = fminf(fmaxf(xva + (11.0f / 21.0f) * r2a, 0.0f), 1.0f);
  float av1 = fminf(fmaxf(xvb + (11.0f / 21.0f) * r2b, 0.0f), 1.0f);
  float sa, sn;
  bsum2(av0 + av1, av0 * kv0 + av1 * kv1, red, sa, sn);
  if (t == 0) contrib[s] = (double)sn - (double)sa * (double)diag;
}

// ---- K4: final reduce (1 block) ----
__global__ __launch_bounds__(256) void k_out(const double* __restrict__ contrib,
                                             float* __restrict__ out) {
  int t = threadIdx.x;
  double s = contrib[t] + contrib[t + 256];
  #pragma unroll
  for (int o = 32; o; o >>= 1) s += __shfl_down(s, o, 64);
  __shared__ double red[4];
  if ((t & 63) == 0) red[t >> 6] = s;
  __syncthreads();
  if (t == 0) out[0] = (float)((red[0] + red[1] + red[2] + red[3]) / 512.0);
}

extern "C" void kernel_launch(void* const* d_in, const int* in_sizes, int n_in,
                              void* d_out, int out_size, void* d_ws, size_t ws_size,
                              hipStream_t stream) {
  const float* x1 = (const float*)d_in[0];
  const float* x2 = (const float*)d_in[1];
  const int* i1 = (const int*)d_in[2];
  const int* i2 = (const int*)d_in[3];

  float* ws = (float*)d_ws;
  float* Km  = ws;                    // 512*1024
  float* rsP = Km + 524288;           // 8*512
  float* Qp  = rsP + 4096;            // 4*512*512
  double* contrib = (double*)(Qp + 1048576);  // 512 doubles (8B aligned)
  float* out = (float*)d_out;

  k_rbf<<<256, 256, 0, stream>>>(x1, x2, i1, i2, Km, rsP);
  k_matmul<<<256, 256, 0, stream>>>(Km, rsP, Qp);
  k_fin3<<<512, 256, 0, stream>>>(Km, rsP, Qp, contrib);
  k_out<<<1, 256, 0, stream>>>(contrib, out);
}